// Round 4
// baseline (304.271 us; speedup 1.0000x reference)
//
#include <hip/hip_runtime.h>
#include <math.h>

#define BB 512
#define SS 50
#define LL 40000
#define DM 80
#define DLOC 56
#define DUSR 12
#define HH 4
#define DH 20
#define DFF 160
#define NPB 625   // 40000/64 column panels

typedef __attribute__((ext_vector_type(8))) short short8v;
typedef __attribute__((ext_vector_type(4))) float f32x4;

__device__ __forceinline__ unsigned short f2bf(float f) {
    unsigned u = __float_as_uint(f);
    u += 0x7fffu + ((u >> 16) & 1u);      // round-to-nearest-even
    return (unsigned short)(u >> 16);
}

__device__ __forceinline__ float gelu_exact(float x) {
    return 0.5f * x * (1.0f + erff(x * 0.70710678118654752f));
}

// =====================================================================
// K_FUSED: per batch row b (512 blocks x 512 threads):
//   phase 0: history compaction (wave 0); also zeroes rowsum[b]
//   phase 1: embed + input LN + PE -> xs[50][80] (LDS)
//   phase 2: K,V for all 50 tokens + Q for token 49 (register-blocked)
//   phase 3: last-token attention + out-proj + LN1 + FF + LN2 + pred1
// Outputs: histval/histloc (compact), gvec (bf16 512x160), rowsum=0
// =====================================================================
__global__ __launch_bounds__(512) void k_fused(
        const int* __restrict__ loc_seq, const int* __restrict__ user_seq,
        const int* __restrict__ wd_seq, const float* __restrict__ start_seq,
        const float* __restrict__ dur_seq, const int* __restrict__ diff_seq,
        const float* __restrict__ loc_emb, const float* __restrict__ user_emb,
        const float* __restrict__ tproj_w, const float* __restrict__ tproj_b,
        const float* __restrict__ in_g, const float* __restrict__ in_b,
        const float* __restrict__ pe,
        const float* __restrict__ attn_in_w, const float* __restrict__ attn_in_b,
        const float* __restrict__ aw, const float* __restrict__ ab,
        const float* __restrict__ n1g, const float* __restrict__ n1b,
        const float* __restrict__ w1, const float* __restrict__ b1,
        const float* __restrict__ w2, const float* __restrict__ b2,
        const float* __restrict__ n2g, const float* __restrict__ n2b,
        const float* __restrict__ pw1, const float* __restrict__ pb1,
        const float* __restrict__ p_decay, const float* __restrict__ p_fw,
        const float* __restrict__ p_hs,
        float* __restrict__ histval, int* __restrict__ histloc,
        unsigned short* __restrict__ gvec, float* __restrict__ rowsum) {
    int b = blockIdx.x, tid = threadIdx.x;
    __shared__ __align__(16) float xs[SS][DM];     // 16000 B
    __shared__ float kv[SS][2 * DM];               // 32000 B  (K | V)
    __shared__ float tf[SS][6];
    __shared__ float rw[SS];
    __shared__ int   loc[SS];
    __shared__ int   usr[SS];
    __shared__ float q[DM];
    __shared__ float sc[HH * SS];
    __shared__ float s_ao[DM];
    __shared__ float xln[DM];
    __shared__ float y[DM];
    __shared__ float z[DM];
    __shared__ float f1[DFF];
    __shared__ float s_stat[2];
    __shared__ float hmax[HH], hsum[HH];

    if (tid == 0) rowsum[b] = 0.f;    // zero the atomic accumulator for pass 0

    // ---- per-token scalars, tf, recency weights ----
    if (tid < SS) {
        int t = tid;
        loc[t] = loc_seq[b * SS + t];
        usr[t] = user_seq[b * SS + t];
        float tr = start_seq[b * SS + t] * (float)(M_PI / 720.0);
        float wrd = (float)wd_seq[b * SS + t] * (float)(2.0 * M_PI / 7.0);
        tf[t][0] = sinf(tr); tf[t][1] = cosf(tr);
        tf[t][2] = log1pf(dur_seq[b * SS + t]) * 0.125f;
        tf[t][3] = sinf(wrd); tf[t][4] = cosf(wrd);
        tf[t][5] = (float)diff_seq[b * SS + t] * (1.f / 7.f);
        rw[t] = powf(p_decay[0], (float)(SS - 1 - t));
    }
    __syncthreads();   // B1: loc/usr/tf/rw ready

    // ---- phase 0: history (wave 0 only, no barriers needed) ----
    if (tid < 64) {
        int t = tid;
        int c = 0; float rmx = 0.f; int first = (t < SS) ? 1 : 0;
        if (t < SS) {
            int my = loc[t];
            for (int j = 0; j < SS; ++j) {
                if (loc[j] == my) {
                    c++; rmx = fmaxf(rmx, rw[j]);
                    if (j < t) first = 0;
                }
            }
        }
        int mc = c;
        #pragma unroll
        for (int m = 1; m < 64; m <<= 1) mc = max(mc, __shfl_xor(mc, m));
        if (t < SS) {
            float val = 0.f;
            if (first) val = p_hs[0] * (rmx + p_fw[0] * ((float)c / (float)max(mc, 1)));
            histval[b * SS + t] = val;
            histloc[b * SS + t] = loc[t];
        }
    }

    // ---- phase 1a: raw feature fill ----
    for (int idx = tid; idx < SS * DM; idx += 512) {
        int t = idx / DM, d = idx % DM;
        float v;
        if (d < DLOC) {
            v = loc_emb[(size_t)loc[t] * DLOC + d];
        } else if (d < DLOC + DUSR) {
            v = user_emb[(size_t)usr[t] * DUSR + (d - DLOC)];
        } else {
            int j = d - (DLOC + DUSR);
            float a = tproj_b[j];
            #pragma unroll
            for (int i = 0; i < 6; ++i) a += tf[t][i] * tproj_w[i * 12 + j];
            v = a;
        }
        xs[t][d] = v;
    }
    __syncthreads();   // B2: raw xs ready

    // ---- phase 1b: per-token LN + PE (wave-level shfl) ----
    {
        int wv = tid >> 6, ln = tid & 63;
        for (int t = wv; t < SS; t += 8) {
            float v0 = xs[t][ln];
            float v1 = (ln < 16) ? xs[t][64 + ln] : 0.f;
            float sm = v0 + v1;
            #pragma unroll
            for (int m = 1; m < 64; m <<= 1) sm += __shfl_xor(sm, m);
            float mean = sm * (1.f / DM);
            float d0 = v0 - mean, d1 = (ln < 16) ? (v1 - mean) : 0.f;
            float vs = d0 * d0 + d1 * d1;
            #pragma unroll
            for (int m = 1; m < 64; m <<= 1) vs += __shfl_xor(vs, m);
            float inv = rsqrtf(vs * (1.f / DM) + 1e-5f);
            xs[t][ln] = d0 * inv * in_g[ln] + in_b[ln] + pe[t * DM + ln];
            if (ln < 16)
                xs[t][64 + ln] = d1 * inv * in_g[64 + ln] + in_b[64 + ln] + pe[t * DM + 64 + ln];
        }
    }
    __syncthreads();   // B3: xs final

    // ---- phase 2: K,V all tokens (tid<320: 5j x 5t regs); Q tok49 (tid 320..399) ----
    if (tid < 320) {
        int jg = tid / 10, tg = tid % 10;          // jg in [0,32), tg in [0,10)
        const float* Wr = attn_in_w + (size_t)(DM + jg * 5) * DM;  // K/V rows
        float acc[5][5];
        #pragma unroll
        for (int u = 0; u < 5; ++u) {
            float bia = attn_in_b[DM + jg * 5 + u];
            #pragma unroll
            for (int v = 0; v < 5; ++v) acc[u][v] = bia;
        }
        #pragma unroll 4
        for (int kc = 0; kc < DM; kc += 4) {
            float4 xq[5];
            #pragma unroll
            for (int v = 0; v < 5; ++v)
                xq[v] = *(const float4*)&xs[tg * 5 + v][kc];
            #pragma unroll
            for (int u = 0; u < 5; ++u) {
                float4 wq = *(const float4*)&Wr[(size_t)u * DM + kc];
                #pragma unroll
                for (int v = 0; v < 5; ++v)
                    acc[u][v] += wq.x * xq[v].x + wq.y * xq[v].y +
                                 wq.z * xq[v].z + wq.w * xq[v].w;
            }
        }
        #pragma unroll
        for (int u = 0; u < 5; ++u)
            #pragma unroll
            for (int v = 0; v < 5; ++v)
                kv[tg * 5 + v][jg * 5 + u] = acc[u][v];
    } else if (tid < 400) {
        int j = tid - 320;
        const float* Wr = attn_in_w + (size_t)j * DM;
        float a = attn_in_b[j];
        #pragma unroll 4
        for (int kc = 0; kc < DM; kc += 4) {
            float4 x4 = *(const float4*)&xs[49][kc];
            float4 w4 = *(const float4*)&Wr[kc];
            a += w4.x * x4.x + w4.y * x4.y + w4.z * x4.z + w4.w * x4.w;
        }
        q[j] = a;
    }
    __syncthreads();   // B4: kv, q ready

    // ---- phase 3: attention for token 49 ----
    if (tid < HH * SS) {
        int h = tid / SS, s = tid % SS;
        float a = 0.f;
        #pragma unroll
        for (int d = 0; d < DH; ++d) a += q[h * DH + d] * kv[s][h * DH + d];
        sc[h * SS + s] = a * 0.22360679774997896f;   // 1/sqrt(20)
    }
    __syncthreads();
    if (tid < HH) {
        float m = -1e30f;
        for (int s = 0; s < SS; ++s) m = fmaxf(m, sc[tid * SS + s]);
        hmax[tid] = m;
    }
    __syncthreads();
    if (tid < HH * SS) sc[tid] = __expf(sc[tid] - hmax[tid / SS]);
    __syncthreads();
    if (tid < HH) {
        float sm2 = 0.f;
        for (int s = 0; s < SS; ++s) sm2 += sc[tid * SS + s];
        hsum[tid] = sm2;
    }
    __syncthreads();
    if (tid < DM) {
        int h = tid / DH, dd = tid % DH;
        float a = 0.f;
        for (int s = 0; s < SS; ++s) a += sc[h * SS + s] * kv[s][DM + h * DH + dd];
        s_ao[tid] = a / hsum[h];
    }
    __syncthreads();
    // x1 = xs[49] + ao @ aw^T + ab
    if (tid < DM) {
        float a = ab[tid];
        const float* ar = aw + (size_t)tid * DM;
        for (int d = 0; d < DM; ++d) a += s_ao[d] * ar[d];
        xln[tid] = xs[49][tid] + a;
    }
    __syncthreads();
    if (tid < 64) {   // LN1 stats
        float v0 = xln[tid], v1 = (tid < 16) ? xln[64 + tid] : 0.f;
        float sm = v0 + v1;
        #pragma unroll
        for (int m = 1; m < 64; m <<= 1) sm += __shfl_xor(sm, m);
        float mean = sm * (1.f / DM);
        float d0 = v0 - mean, d1 = (tid < 16) ? (v1 - mean) : 0.f;
        float vs = d0 * d0 + d1 * d1;
        #pragma unroll
        for (int m = 1; m < 64; m <<= 1) vs += __shfl_xor(vs, m);
        if (tid == 0) { s_stat[0] = mean; s_stat[1] = rsqrtf(vs * (1.f / DM) + 1e-5f); }
    }
    __syncthreads();
    if (tid < DM) y[tid] = (xln[tid] - s_stat[0]) * s_stat[1] * n1g[tid] + n1b[tid];
    __syncthreads();
    if (tid < DFF) {
        float a = b1[tid];
        for (int d = 0; d < DM; ++d) a += y[d] * w1[(size_t)d * DFF + tid];
        f1[tid] = gelu_exact(a);
    }
    __syncthreads();
    if (tid < DM) {
        float a = b2[tid];
        for (int j = 0; j < DFF; ++j) a += f1[j] * w2[(size_t)j * DM + tid];
        xln[tid] = y[tid] + a;
    }
    __syncthreads();
    if (tid < 64) {   // LN2 stats
        float v0 = xln[tid], v1 = (tid < 16) ? xln[64 + tid] : 0.f;
        float sm = v0 + v1;
        #pragma unroll
        for (int m = 1; m < 64; m <<= 1) sm += __shfl_xor(sm, m);
        float mean = sm * (1.f / DM);
        float d0 = v0 - mean, d1 = (tid < 16) ? (v1 - mean) : 0.f;
        float vs = d0 * d0 + d1 * d1;
        #pragma unroll
        for (int m = 1; m < 64; m <<= 1) vs += __shfl_xor(vs, m);
        if (tid == 0) { s_stat[0] = mean; s_stat[1] = rsqrtf(vs * (1.f / DM) + 1e-5f); }
    }
    __syncthreads();
    if (tid < DM) z[tid] = (xln[tid] - s_stat[0]) * s_stat[1] * n2g[tid] + n2b[tid];
    __syncthreads();
    if (tid < DFF) {
        float a = pb1[tid];
        for (int d = 0; d < DM; ++d) a += z[d] * pw1[(size_t)d * DFF + tid];
        gvec[b * DFF + tid] = f2bf(gelu_exact(a));
    }
}

// =====================================================================
// K_MFMA: bf16 MFMA logits GEMM, tile 128x64, K=160 whole, 4 waves.
// Wave w: 64x32 quadrant (wr=(w>>1)*64, wc=(w&1)*32), acc 4x2 f32x4.
// WRITE=0: atomicAdd per-row exp-sums into rowsum[512].
// WRITE=1: out = exp(logit) * (mw*L / rowsum[row]).
// Max-subtraction skipped: |logits| <~ 0.25 (0.02-std weights), exp safe.
// =====================================================================
template<int WRITE>
__global__ __launch_bounds__(256) void k_mfma(
        const unsigned short* __restrict__ Abf,   // 512x160 bf16
        const float* __restrict__ B,              // 160x40000 f32 (pred_w2)
        const float* __restrict__ bias,           // 40000 (pred_b2)
        const float* __restrict__ p_mw,           // scalar model_weight
        float* __restrict__ rowsum,               // 512 atomic exp-sums
        float* __restrict__ out) {                // 512x40000
    int by = blockIdx.x;            // 0..3  (M) -- fast dim
    int bx = blockIdx.y;            // 0..624 (N)
    int m0 = by * 128, n0 = bx * 64;
    int tid = threadIdx.x;
    int l = tid & 63, w = tid >> 6;
    __shared__ __align__(16) unsigned short As2[20][128][8];  // 40 KB
    __shared__ __align__(16) unsigned short Bs2[20][64][8];   // 20 KB
    __shared__ float rsum[128][2];
    // A stage: linear copy of 128x160 bf16 (2560 x 16B), scattered to [kt][row]
    #pragma unroll
    for (int i = 0; i < 10; ++i) {
        int gid = i * 256 + tid;
        int row = gid / 20, kt = gid % 20;
        uint4 val = *(const uint4*)&Abf[(size_t)(m0 + row) * DFF + kt * 8];
        *(uint4*)&As2[kt][row][0] = val;
    }
    // B stage: fp32 -> bf16; lane l = column (coalesced per k)
    #pragma unroll
    for (int i = 0; i < 5; ++i) {
        int kt = w + 4 * i;
        unsigned short pk[8];
        #pragma unroll
        for (int j = 0; j < 8; ++j)
            pk[j] = f2bf(B[(size_t)(kt * 8 + j) * LL + n0 + l]);
        *(uint4*)&Bs2[kt][l][0] = *(const uint4*)pk;
    }
    __syncthreads();
    int wr = (w >> 1) * 64, wc = (w & 1) * 32;
    int lg = l >> 4, lr = l & 15;
    f32x4 acc[4][2] = {};
    #pragma unroll
    for (int step = 0; step < 5; ++step) {
        int ktb = step * 4 + lg;
        short8v b0 = *reinterpret_cast<const short8v*>(&Bs2[ktb][wc + lr][0]);
        short8v b1 = *reinterpret_cast<const short8v*>(&Bs2[ktb][wc + 16 + lr][0]);
        #pragma unroll
        for (int mi = 0; mi < 4; ++mi) {
            short8v a = *reinterpret_cast<const short8v*>(&As2[ktb][wr + mi * 16 + lr][0]);
            acc[mi][0] = __builtin_amdgcn_mfma_f32_16x16x32_bf16(a, b0, acc[mi][0], 0, 0, 0);
            acc[mi][1] = __builtin_amdgcn_mfma_f32_16x16x32_bf16(a, b1, acc[mi][1], 0, 0, 0);
        }
    }
    float bia0 = bias[n0 + wc + lr];
    float bia1 = bias[n0 + wc + 16 + lr];
    if (WRITE) {
        float mwL = p_mw[0] * (float)LL;
        #pragma unroll
        for (int mi = 0; mi < 4; ++mi) {
            #pragma unroll
            for (int r = 0; r < 4; ++r) {
                int row = m0 + wr + mi * 16 + lg * 4 + r;
                float scv = mwL / rowsum[row];
                out[(size_t)row * LL + n0 + wc + lr] = __expf(acc[mi][0][r] + bia0) * scv;
                out[(size_t)row * LL + n0 + wc + 16 + lr] = __expf(acc[mi][1][r] + bia1) * scv;
            }
        }
    } else {
        #pragma unroll
        for (int mi = 0; mi < 4; ++mi) {
            #pragma unroll
            for (int r = 0; r < 4; ++r) {
                float sv = __expf(acc[mi][0][r] + bia0) + __expf(acc[mi][1][r] + bia1);
                #pragma unroll
                for (int mk = 1; mk < 16; mk <<= 1) sv += __shfl_xor(sv, mk);
                if (lr == 0) rsum[wr + mi * 16 + lg * 4 + r][w & 1] = sv;
            }
        }
        __syncthreads();
        if (tid < 128)
            atomicAdd(&rowsum[m0 + tid], rsum[tid][0] + rsum[tid][1]);
    }
}

// ---------------- scatter history into output ----------------
__global__ void k_scatter(const float* __restrict__ histval,
                          const int* __restrict__ histloc,
                          float* __restrict__ out) {
    int b = blockIdx.x, t = threadIdx.x;
    if (t < SS) {
        float v = histval[b * SS + t];
        if (v != 0.f) atomicAdd(&out[(size_t)b * LL + histloc[b * SS + t]], v);
    }
}

extern "C" void kernel_launch(void* const* d_in, const int* in_sizes, int n_in,
                              void* d_out, int out_size, void* d_ws, size_t ws_size,
                              hipStream_t stream) {
    const int*   loc_seq   = (const int*)d_in[0];
    const int*   user_seq  = (const int*)d_in[1];
    const int*   wd_seq    = (const int*)d_in[2];
    const float* start_seq = (const float*)d_in[3];
    const float* dur_seq   = (const float*)d_in[4];
    const int*   diff_seq  = (const int*)d_in[5];
    // d_in[6] = mask: all-ones by construction -> unused
    const float* loc_emb   = (const float*)d_in[7];
    const float* user_emb  = (const float*)d_in[8];
    const float* tproj_w   = (const float*)d_in[9];
    const float* tproj_b   = (const float*)d_in[10];
    const float* in_g      = (const float*)d_in[11];
    const float* in_b      = (const float*)d_in[12];
    const float* attn_in_w = (const float*)d_in[13];
    const float* attn_in_b = (const float*)d_in[14];
    const float* attn_out_w= (const float*)d_in[15];
    const float* attn_out_b= (const float*)d_in[16];
    const float* n1g       = (const float*)d_in[17];
    const float* n1b       = (const float*)d_in[18];
    const float* ff_w1     = (const float*)d_in[19];
    const float* ff_b1     = (const float*)d_in[20];
    const float* ff_w2     = (const float*)d_in[21];
    const float* ff_b2     = (const float*)d_in[22];
    const float* n2g       = (const float*)d_in[23];
    const float* n2b       = (const float*)d_in[24];
    const float* pw1       = (const float*)d_in[25];
    const float* pb1       = (const float*)d_in[26];
    const float* pw2       = (const float*)d_in[27];
    const float* pb2       = (const float*)d_in[28];
    const float* p_decay   = (const float*)d_in[29];
    const float* p_fw      = (const float*)d_in[30];
    const float* p_hs      = (const float*)d_in[31];
    const float* p_mw      = (const float*)d_in[32];
    const float* pe        = (const float*)d_in[33];
    float* out = (float*)d_out;

    float* ws        = (float*)d_ws;
    float* rowsum    = ws;                          // 512
    float* histval   = rowsum + 512;                // 25600
    int*   histloc   = (int*)(histval + 25600);     // 25600
    unsigned short* gvec_b = (unsigned short*)(histloc + 25600);  // 512*160 bf16

    k_fused<<<BB, 512, 0, stream>>>(loc_seq, user_seq, wd_seq, start_seq, dur_seq,
                                    diff_seq, loc_emb, user_emb, tproj_w, tproj_b,
                                    in_g, in_b, pe, attn_in_w, attn_in_b,
                                    attn_out_w, attn_out_b, n1g, n1b,
                                    ff_w1, ff_b1, ff_w2, ff_b2, n2g, n2b,
                                    pw1, pb1, p_decay, p_fw, p_hs,
                                    histval, histloc, gvec_b, rowsum);
    dim3 g4(4, NPB);
    k_mfma<0><<<g4, 256, 0, stream>>>(gvec_b, pw2, pb2, p_mw, rowsum, out);
    k_mfma<1><<<g4, 256, 0, stream>>>(gvec_b, pw2, pb2, p_mw, rowsum, out);
    k_scatter<<<BB, 64, 0, stream>>>(histval, histloc, out);
}

// Round 5
// 279.817 us; speedup vs baseline: 1.0874x; 1.0874x over previous
//
#include <hip/hip_runtime.h>
#include <math.h>

#define BB 512
#define SS 50
#define LL 40000
#define DM 80
#define DLOC 56
#define DUSR 12
#define HH 4
#define DH 20
#define DFF 160

typedef __attribute__((ext_vector_type(8))) short short8v;
typedef __attribute__((ext_vector_type(4))) float f32x4;

__device__ __forceinline__ unsigned short f2bf(float f) {
    unsigned u = __float_as_uint(f);
    u += 0x7fffu + ((u >> 16) & 1u);      // round-to-nearest-even
    return (unsigned short)(u >> 16);
}

__device__ __forceinline__ float gelu_exact(float x) {
    return 0.5f * x * (1.0f + erff(x * 0.70710678118654752f));
}

// =====================================================================
// K_FUSED: one block (256 thr) per batch row. Attention is folded:
//   u_h = W_k[h]^T q_h  ->  score_sh = (u_h . x_s)/sqrt(20)   (k-bias cancels)
//   ao_h = W_v[h] (sum_s a_sh x_s) + b_v                      (sum a = 1)
// All GEMVs: thread-per-output, K serial, weight reads lane-consecutive.
// xs kept in LDS twice (row-major + transposed) for conflict-free reads.
// =====================================================================
__global__ __launch_bounds__(256) void k_fused(
        const int* __restrict__ loc_seq, const int* __restrict__ user_seq,
        const int* __restrict__ wd_seq, const float* __restrict__ start_seq,
        const float* __restrict__ dur_seq, const int* __restrict__ diff_seq,
        const float* __restrict__ loc_emb, const float* __restrict__ user_emb,
        const float* __restrict__ tproj_w, const float* __restrict__ tproj_b,
        const float* __restrict__ in_g, const float* __restrict__ in_b,
        const float* __restrict__ pe,
        const float* __restrict__ Wqkv, const float* __restrict__ bqkv,
        const float* __restrict__ aw, const float* __restrict__ ab,
        const float* __restrict__ n1g, const float* __restrict__ n1b,
        const float* __restrict__ w1, const float* __restrict__ b1,
        const float* __restrict__ w2, const float* __restrict__ b2,
        const float* __restrict__ n2g, const float* __restrict__ n2b,
        const float* __restrict__ pw1, const float* __restrict__ pb1,
        const float* __restrict__ p_decay, const float* __restrict__ p_fw,
        const float* __restrict__ p_hs,
        float* __restrict__ histval, int* __restrict__ histloc,
        unsigned short* __restrict__ gvec, float* __restrict__ rowsum) {
    int b = blockIdx.x, tid = threadIdx.x;
    int w = tid >> 6, ln = tid & 63;
    __shared__ __align__(16) float xs[SS][DM];    // 16 KB row-major
    __shared__ float xsT[DM][SS];                 // 16 KB transposed
    __shared__ float tf6[SS][6];
    __shared__ float rw[SS];
    __shared__ int   loc[SS];
    __shared__ int   usr[SS];
    __shared__ float qr[DM];
    __shared__ float uu[HH][DM];
    __shared__ float scw[HH][SS];
    __shared__ float wsm[HH][DM];
    __shared__ float ao[DM];
    __shared__ float v1[DM];
    __shared__ float v2[DM];
    __shared__ float f1[DFF];
    __shared__ float stat[2];

    if (tid == 0) rowsum[b] = 0.f;   // zero atomic accumulator for GEMM pass 0

    // ---- P0: per-token scalars ----
    if (tid < SS) {
        int t = tid;
        loc[t] = loc_seq[b * SS + t];
        usr[t] = user_seq[b * SS + t];
        float tr = start_seq[b * SS + t] * (float)(M_PI / 720.0);
        float wrd = (float)wd_seq[b * SS + t] * (float)(2.0 * M_PI / 7.0);
        tf6[t][0] = sinf(tr); tf6[t][1] = cosf(tr);
        tf6[t][2] = log1pf(dur_seq[b * SS + t]) * 0.125f;
        tf6[t][3] = sinf(wrd); tf6[t][4] = cosf(wrd);
        tf6[t][5] = (float)diff_seq[b * SS + t] * (1.f / 7.f);
        rw[t] = exp2f((float)(SS - 1 - t) * log2f(p_decay[0]));
    }
    __syncthreads();

    // ---- P1: embed fill (all threads) ----
    for (int idx = tid; idx < SS * DM; idx += 256) {
        int t = idx / DM, d = idx - t * DM;
        float v;
        if (d < DLOC) {
            v = loc_emb[(size_t)loc[t] * DLOC + d];
        } else if (d < DLOC + DUSR) {
            v = user_emb[(size_t)usr[t] * DUSR + (d - DLOC)];
        } else {
            int j = d - (DLOC + DUSR);
            float a = tproj_b[j];
            #pragma unroll
            for (int i = 0; i < 6; ++i) a += tf6[t][i] * tproj_w[i * 12 + j];
            v = a;
        }
        xs[t][d] = v;
    }
    __syncthreads();

    // ---- P2: per-token LN + PE (wave per token), dual-store ----
    for (int t = w; t < SS; t += 4) {
        float a0 = xs[t][ln];
        float a1 = (ln < 16) ? xs[t][64 + ln] : 0.f;
        float sm = a0 + a1;
        #pragma unroll
        for (int m = 1; m < 64; m <<= 1) sm += __shfl_xor(sm, m);
        float mean = sm * (1.f / DM);
        float d0 = a0 - mean, d1 = (ln < 16) ? (a1 - mean) : 0.f;
        float vs = d0 * d0 + d1 * d1;
        #pragma unroll
        for (int m = 1; m < 64; m <<= 1) vs += __shfl_xor(vs, m);
        float inv = rsqrtf(vs * (1.f / DM) + 1e-5f);
        float r0 = d0 * inv * in_g[ln] + in_b[ln] + pe[t * DM + ln];
        xs[t][ln] = r0; xsT[ln][t] = r0;
        if (ln < 16) {
            float r1 = d1 * inv * in_g[64 + ln] + in_b[64 + ln] + pe[t * DM + 64 + ln];
            xs[t][64 + ln] = r1; xsT[64 + ln][t] = r1;
        }
    }
    __syncthreads();

    // ---- P3: wave0 = history; waves1-2 = q_raw for token 49 ----
    if (w == 0) {
        int t = ln;
        int c = 0; float rmx = 0.f; int first = (t < SS) ? 1 : 0;
        if (t < SS) {
            int my = loc[t];
            for (int j = 0; j < SS; ++j) {
                if (loc[j] == my) {
                    c++; rmx = fmaxf(rmx, rw[j]);
                    if (j < t) first = 0;
                }
            }
        }
        int mc = c;
        #pragma unroll
        for (int m = 1; m < 64; m <<= 1) mc = max(mc, __shfl_xor(mc, m));
        if (t < SS) {
            float val = 0.f;
            if (first) val = p_hs[0] * (rmx + p_fw[0] * ((float)c / (float)max(mc, 1)));
            histval[b * SS + t] = val;
            histloc[b * SS + t] = loc[t];
        }
    } else if (tid >= 64 && tid < 64 + DM) {
        int j = tid - 64;
        const float* Wr = Wqkv + (size_t)j * DM;
        float a = bqkv[j];
        for (int d = 0; d < DM; ++d) a += xs[49][d] * Wr[d];
        qr[j] = a;
    }
    __syncthreads();

    // ---- P4: u_h[d] = sum_j qr[h*20+j] * Wk[(80+h*20+j)][d]  (320 outputs) ----
    {
        int idx = tid;
        float a0 = 0.f, a1 = 0.f;
        int h0 = idx / DM, d0i = idx - h0 * DM;
        #pragma unroll 4
        for (int j = 0; j < DH; ++j)
            a0 += qr[h0 * DH + j] * Wqkv[(size_t)(DM + h0 * DH + j) * DM + d0i];
        int idx1 = tid + 256;
        int h1 = idx1 / DM, d1i = idx1 - h1 * DM;
        if (tid < 64) {
            #pragma unroll 4
            for (int j = 0; j < DH; ++j)
                a1 += qr[h1 * DH + j] * Wqkv[(size_t)(DM + h1 * DH + j) * DM + d1i];
        }
        uu[h0][d0i] = a0;
        if (tid < 64) uu[h1][d1i] = a1;
    }
    __syncthreads();

    // ---- P5: scores (200 outputs, K=80 over xsT: conflict-free) ----
    if (tid < HH * SS) {
        int h = tid / SS, s = tid - h * SS;
        float a = 0.f;
        #pragma unroll 4
        for (int d = 0; d < DM; ++d) a += uu[h][d] * xsT[d][s];
        scw[h][s] = a * 0.22360679774997896f;   // 1/sqrt(20)
    }
    __syncthreads();

    // ---- P6: softmax per head (wave w = head h) ----
    {
        float v = (ln < SS) ? scw[w][ln] : -1e30f;
        float m = v;
        #pragma unroll
        for (int mk = 1; mk < 64; mk <<= 1) m = fmaxf(m, __shfl_xor(m, mk));
        float e = (ln < SS) ? __expf(v - m) : 0.f;
        float sm = e;
        #pragma unroll
        for (int mk = 1; mk < 64; mk <<= 1) sm += __shfl_xor(sm, mk);
        if (ln < SS) scw[w][ln] = e / sm;
    }
    __syncthreads();

    // ---- P7: wsum_h[d] = sum_s a_sh * xs[s][d]  (320 outputs) ----
    {
        int idx = tid;
        int h0 = idx / DM, d0i = idx - h0 * DM;
        float a0 = 0.f, a1 = 0.f;
        #pragma unroll 5
        for (int s = 0; s < SS; ++s) a0 += scw[h0][s] * xs[s][d0i];
        int idx1 = tid + 256;
        int h1 = idx1 / DM, d1i = idx1 - h1 * DM;
        if (tid < 64) {
            #pragma unroll 5
            for (int s = 0; s < SS; ++s) a1 += scw[h1][s] * xs[s][d1i];
        }
        wsm[h0][d0i] = a0;
        if (tid < 64) wsm[h1][d1i] = a1;
    }
    __syncthreads();

    // ---- P8: ao[hj] = b_v + Wv[(160+hj)] . wsum_h  (80 outputs) ----
    if (tid < DM) {
        int h = tid / DH;
        const float* Wr = Wqkv + (size_t)(2 * DM + tid) * DM;
        float a = bqkv[2 * DM + tid];
        for (int d = 0; d < DM; ++d) a += Wr[d] * wsm[h][d];
        ao[tid] = a;
    }
    __syncthreads();

    // ---- P9: x1 = xs49 + ao @ aw^T + ab ----
    if (tid < DM) {
        float a = ab[tid];
        const float* ar = aw + (size_t)tid * DM;
        for (int d = 0; d < DM; ++d) a += ao[d] * ar[d];
        v1[tid] = xs[49][tid] + a;
    }
    __syncthreads();
    // ---- LN1 stats (wave0) ----
    if (w == 0) {
        float a0 = (ln < DM) ? v1[ln] : 0.f;
        float a1 = (ln < 16) ? v1[64 + ln] : 0.f;
        float sm = a0 + a1;
        #pragma unroll
        for (int m = 1; m < 64; m <<= 1) sm += __shfl_xor(sm, m);
        float mean = sm * (1.f / DM);
        float d0 = (ln < DM) ? a0 - mean : 0.f, d1 = (ln < 16) ? a1 - mean : 0.f;
        float vs = d0 * d0 + d1 * d1;
        #pragma unroll
        for (int m = 1; m < 64; m <<= 1) vs += __shfl_xor(vs, m);
        if (ln == 0) { stat[0] = mean; stat[1] = rsqrtf(vs * (1.f / DM) + 1e-5f); }
    }
    __syncthreads();
    if (tid < DM) v2[tid] = (v1[tid] - stat[0]) * stat[1] * n1g[tid] + n1b[tid];  // y
    __syncthreads();

    // ---- P11: f1 = gelu(y @ w1 + b1)  (160 outputs, coalesced w1) ----
    if (tid < DFF) {
        float a = b1[tid];
        for (int d = 0; d < DM; ++d) a += v2[d] * w1[(size_t)d * DFF + tid];
        f1[tid] = gelu_exact(a);
    }
    __syncthreads();

    // ---- P12: x2 = y + f1 @ w2 + b2 ----
    if (tid < DM) {
        float a = b2[tid];
        for (int j = 0; j < DFF; ++j) a += f1[j] * w2[(size_t)j * DM + tid];
        v1[tid] = v2[tid] + a;
    }
    __syncthreads();
    // ---- LN2 stats (wave0) ----
    if (w == 0) {
        float a0 = (ln < DM) ? v1[ln] : 0.f;
        float a1 = (ln < 16) ? v1[64 + ln] : 0.f;
        float sm = a0 + a1;
        #pragma unroll
        for (int m = 1; m < 64; m <<= 1) sm += __shfl_xor(sm, m);
        float mean = sm * (1.f / DM);
        float d0 = (ln < DM) ? a0 - mean : 0.f, d1 = (ln < 16) ? a1 - mean : 0.f;
        float vs = d0 * d0 + d1 * d1;
        #pragma unroll
        for (int m = 1; m < 64; m <<= 1) vs += __shfl_xor(vs, m);
        if (ln == 0) { stat[0] = mean; stat[1] = rsqrtf(vs * (1.f / DM) + 1e-5f); }
    }
    __syncthreads();
    if (tid < DM) v2[tid] = (v1[tid] - stat[0]) * stat[1] * n2g[tid] + n2b[tid];  // z
    __syncthreads();

    // ---- P14: gvec = bf16(gelu(z @ pw1 + pb1)) ----
    if (tid < DFF) {
        float a = pb1[tid];
        for (int d = 0; d < DM; ++d) a += v2[d] * pw1[(size_t)d * DFF + tid];
        gvec[b * DFF + tid] = f2bf(gelu_exact(a));
    }
}

// =====================================================================
// K_PREP: transpose pred_w2 (f32 [160][40000]) -> bf16 Bp [40000][160]
// =====================================================================
__global__ __launch_bounds__(256) void k_prep(const float* __restrict__ B,
                                              unsigned short* __restrict__ Bp) {
    int n = blockIdx.x * 256 + threadIdx.x;
    if (n >= LL) return;
    #pragma unroll
    for (int c = 0; c < 4; ++c) {
        int k0 = c * 40;
        unsigned pk[20];
        #pragma unroll
        for (int jj = 0; jj < 20; ++jj) {
            float lo = B[(size_t)(k0 + 2 * jj) * LL + n];
            float hi = B[(size_t)(k0 + 2 * jj + 1) * LL + n];
            pk[jj] = (unsigned)f2bf(lo) | ((unsigned)f2bf(hi) << 16);
        }
        uint4* dst = (uint4*)&Bp[(size_t)n * DFF + k0];
        #pragma unroll
        for (int q = 0; q < 5; ++q)
            dst[q] = make_uint4(pk[q * 4], pk[q * 4 + 1], pk[q * 4 + 2], pk[q * 4 + 3]);
    }
}

// =====================================================================
// K_MFMA: LDS-free bf16 GEMM. Tile M=256 x N=64, K=160, 512 thr (8 waves).
// Wave w: rows (w>>1)*64, cols (w&1)*32. Fragments loaded directly from
// global (A = gvec [512][160] bf16, B = Bp [40000][160] bf16), L2/L3-hot.
// WRITE=0: atomicAdd per-row exp-sums into rowsum. WRITE=1: final store.
// Max-subtraction skipped: |logits| <~ 0.3 -> exp safe.
// =====================================================================
template<int WRITE>
__global__ __launch_bounds__(512) void k_mfma(
        const unsigned short* __restrict__ Abf,   // 512x160 bf16
        const unsigned short* __restrict__ Bp,    // 40000x160 bf16
        const float* __restrict__ bias,           // 40000
        const float* __restrict__ p_mw,
        float* __restrict__ rowsum,               // 512
        float* __restrict__ out) {                // 512x40000
    int by = blockIdx.x;            // 0..1   (M)
    int bx = blockIdx.y;            // 0..624 (N)
    int m0 = by * 256, n0 = bx * 64;
    int tid = threadIdx.x;
    int l = tid & 63, w = tid >> 6;
    int lr = l & 15, lg = l >> 4;
    int wr = (w >> 1) * 64, wc = (w & 1) * 32;
    __shared__ float prs[256][2];

    f32x4 acc[4][2] = {};
    const short8v* Arow[4];
    #pragma unroll
    for (int mi = 0; mi < 4; ++mi)
        Arow[mi] = (const short8v*)&Abf[(size_t)(m0 + wr + mi * 16 + lr) * DFF];
    const short8v* B0 = (const short8v*)&Bp[(size_t)(n0 + wc + lr) * DFF];
    const short8v* B1 = (const short8v*)&Bp[(size_t)(n0 + wc + 16 + lr) * DFF];

    #pragma unroll
    for (int step = 0; step < 5; ++step) {
        int kq = step * 4 + lg;     // 16B-granule index into the 160-k row
        short8v b0 = B0[kq];
        short8v b1 = B1[kq];
        #pragma unroll
        for (int mi = 0; mi < 4; ++mi) {
            short8v a = Arow[mi][kq];
            acc[mi][0] = __builtin_amdgcn_mfma_f32_16x16x32_bf16(a, b0, acc[mi][0], 0, 0, 0);
            acc[mi][1] = __builtin_amdgcn_mfma_f32_16x16x32_bf16(a, b1, acc[mi][1], 0, 0, 0);
        }
    }
    float bia0 = bias[n0 + wc + lr];
    float bia1 = bias[n0 + wc + 16 + lr];
    if (WRITE) {
        float mwL = p_mw[0] * (float)LL;
        #pragma unroll
        for (int mi = 0; mi < 4; ++mi) {
            #pragma unroll
            for (int r = 0; r < 4; ++r) {
                int row = m0 + wr + mi * 16 + lg * 4 + r;
                float scl = mwL / rowsum[row];
                out[(size_t)row * LL + n0 + wc + lr]      = __expf(acc[mi][0][r] + bia0) * scl;
                out[(size_t)row * LL + n0 + wc + 16 + lr] = __expf(acc[mi][1][r] + bia1) * scl;
            }
        }
    } else {
        #pragma unroll
        for (int mi = 0; mi < 4; ++mi) {
            #pragma unroll
            for (int r = 0; r < 4; ++r) {
                float sv = __expf(acc[mi][0][r] + bia0) + __expf(acc[mi][1][r] + bia1);
                #pragma unroll
                for (int mk = 1; mk < 16; mk <<= 1) sv += __shfl_xor(sv, mk);
                if (lr == 0) prs[wr + mi * 16 + lg * 4 + r][w & 1] = sv;
            }
        }
        __syncthreads();
        if (tid < 256)
            atomicAdd(&rowsum[m0 + tid], prs[tid][0] + prs[tid][1]);
    }
}

// ---------------- scatter history into output ----------------
__global__ void k_scatter(const float* __restrict__ histval,
                          const int* __restrict__ histloc,
                          float* __restrict__ out) {
    int b = blockIdx.x, t = threadIdx.x;
    if (t < SS) {
        float v = histval[b * SS + t];
        if (v != 0.f) atomicAdd(&out[(size_t)b * LL + histloc[b * SS + t]], v);
    }
}

extern "C" void kernel_launch(void* const* d_in, const int* in_sizes, int n_in,
                              void* d_out, int out_size, void* d_ws, size_t ws_size,
                              hipStream_t stream) {
    const int*   loc_seq   = (const int*)d_in[0];
    const int*   user_seq  = (const int*)d_in[1];
    const int*   wd_seq    = (const int*)d_in[2];
    const float* start_seq = (const float*)d_in[3];
    const float* dur_seq   = (const float*)d_in[4];
    const int*   diff_seq  = (const int*)d_in[5];
    // d_in[6] = mask: all-ones by construction -> unused
    const float* loc_emb   = (const float*)d_in[7];
    const float* user_emb  = (const float*)d_in[8];
    const float* tproj_w   = (const float*)d_in[9];
    const float* tproj_b   = (const float*)d_in[10];
    const float* in_g      = (const float*)d_in[11];
    const float* in_b      = (const float*)d_in[12];
    const float* attn_in_w = (const float*)d_in[13];
    const float* attn_in_b = (const float*)d_in[14];
    const float* attn_out_w= (const float*)d_in[15];
    const float* attn_out_b= (const float*)d_in[16];
    const float* n1g       = (const float*)d_in[17];
    const float* n1b       = (const float*)d_in[18];
    const float* ff_w1     = (const float*)d_in[19];
    const float* ff_b1     = (const float*)d_in[20];
    const float* ff_w2     = (const float*)d_in[21];
    const float* ff_b2     = (const float*)d_in[22];
    const float* n2g       = (const float*)d_in[23];
    const float* n2b       = (const float*)d_in[24];
    const float* pw1       = (const float*)d_in[25];
    const float* pb1       = (const float*)d_in[26];
    const float* pw2       = (const float*)d_in[27];
    const float* pb2       = (const float*)d_in[28];
    const float* p_decay   = (const float*)d_in[29];
    const float* p_fw      = (const float*)d_in[30];
    const float* p_hs      = (const float*)d_in[31];
    const float* p_mw      = (const float*)d_in[32];
    const float* pe        = (const float*)d_in[33];
    float* out = (float*)d_out;

    char* base = (char*)d_ws;
    unsigned short* Bp = (unsigned short*)base;                 // 40000*160*2 = 12.8 MB
    float* rowsum  = (float*)(base + (size_t)LL * DFF * 2);     // 512
    float* histval = rowsum + 512;                              // 25600
    int*   histloc = (int*)(histval + 25600);                   // 25600
    unsigned short* gvec = (unsigned short*)(histloc + 25600);  // 512*160 bf16

    k_fused<<<BB, 256, 0, stream>>>(loc_seq, user_seq, wd_seq, start_seq, dur_seq,
                                    diff_seq, loc_emb, user_emb, tproj_w, tproj_b,
                                    in_g, in_b, pe, attn_in_w, attn_in_b,
                                    attn_out_w, attn_out_b, n1g, n1b,
                                    ff_w1, ff_b1, ff_w2, ff_b2, n2g, n2b,
                                    pw1, pb1, p_decay, p_fw, p_hs,
                                    histval, histloc, gvec, rowsum);
    k_prep<<<(LL + 255) / 256, 256, 0, stream>>>(pw2, Bp);
    dim3 g4(2, 625);
    k_mfma<0><<<g4, 512, 0, stream>>>(gvec, Bp, pb2, p_mw, rowsum, out);
    k_mfma<1><<<g4, 512, 0, stream>>>(gvec, Bp, pb2, p_mw, rowsum, out);
    k_scatter<<<BB, 64, 0, stream>>>(histval, histloc, out);
}